// Round 5
// baseline (870.834 us; speedup 1.0000x reference)
//
#include <hip/hip_runtime.h>
#include <math.h>

#define NB 4        // batch pairs
#define N 4096      // points
#define CF 640      // feature dim

typedef _Float16 f16;
typedef _Float16 f16x8 __attribute__((ext_vector_type(8)));
typedef _Float16 f16x4 __attribute__((ext_vector_type(4)));
typedef float    f32x4 __attribute__((ext_vector_type(4)));
typedef unsigned int u32;

// ---------------- workspace layout (byte offsets) ----------------
// fnT  : 8*N*CF fp16 (normalized features, (b,n,c)); DEAD after gemm_k ->
//        reused as ktapF (NB*256*N f32 = 16.8MB <= 41.9MB) by fused_iter.
// rnorm: 8*N float  (aliased as rowsum later)
// bvec : NB*N float
// Kh   : NB*N*N fp16 (fp16 shadow of K for Sinkhorn)
// ktapG: NB*64*N f32 (gemm-folded first column-sum partials, 32 slots used)
// fp32 K itself lives in d_out's T region (finalized in place).
#define OFF_FNT   0ll
#define OFF_RNORM (OFF_FNT + 8ll*N*CF*2)
#define OFF_BVEC  (OFF_RNORM + 8ll*N*4)
#define OFF_SCR   (OFF_BVEC + (long long)NB*N*4)
#define OFF_KTAP  (OFF_SCR + (long long)NB*N*N*2)
#define REQ_H     (OFF_KTAP + (long long)NB*64*N*4)
#define REQ_F     (OFF_SCR + (long long)NB*64*N*4)

__device__ inline void async_copy16(void* lds, const void* g) {
    __builtin_amdgcn_global_load_lds(
        (const __attribute__((address_space(1))) u32*)g,
        (__attribute__((address_space(3))) u32*)lds,
        16, 0, 0);
}

__device__ inline float wave_sum(float s) {
    s += __shfl_down(s, 32);
    s += __shfl_down(s, 16);
    s += __shfl_down(s, 8);
    s += __shfl_down(s, 4);
    s += __shfl_down(s, 2);
    s += __shfl_down(s, 1);
    return s;
}

// ---------------- pass 1: per-point inverse norms ----------------
__global__ __launch_bounds__(256) void rnorm_kernel(const float* __restrict__ pf,
                                                    float* __restrict__ rnorm) {
    int idx = blockIdx.x * 256 + threadIdx.x;   // over 8*4096
    int n = idx & (N - 1);
    int b = idx >> 12;
    const float* src = pf + (size_t)b * CF * N + n;
    float s = 0.f;
    for (int c = 0; c < CF; ++c) { float v = src[(size_t)c * N]; s = fmaf(v, v, s); }
    rnorm[idx] = 1.0f / sqrtf(s + 1e-8f);
}

// ---------------- pass 2: transpose (c,n)->(n,c), scale, fp16 ----------------
__global__ __launch_bounds__(256) void transpose_kernel(const float* __restrict__ pf,
                                                        const float* __restrict__ rnorm,
                                                        f16* __restrict__ fnT) {
    __shared__ float tile[64][65];
    int b  = blockIdx.z;
    int c0 = blockIdx.x * 64;
    int n1 = blockIdx.y * 64;
    int t  = threadIdx.x;

    int c_l = t >> 4;               // 0..15
    int n_l4 = (t & 15) * 4;        // 0..60
    #pragma unroll
    for (int i = 0; i < 4; ++i) {
        int c = c_l + i * 16;
        float4 v = *(const float4*)(pf + (size_t)(b * CF + c0 + c) * N + n1 + n_l4);
        tile[c][n_l4 + 0] = v.x; tile[c][n_l4 + 1] = v.y;
        tile[c][n_l4 + 2] = v.z; tile[c][n_l4 + 3] = v.w;
    }
    __syncthreads();

    int n_l = t >> 2;               // 0..63
    int c_g = (t & 3) * 16;         // 0,16,32,48
    float rn = rnorm[b * N + n1 + n_l];
    f16 tmp[16] __attribute__((aligned(16)));
    #pragma unroll
    for (int i = 0; i < 16; ++i)
        tmp[i] = (f16)(tile[c_g + i][n_l] * rn);
    f16* dst = fnT + (size_t)(b * N + n1 + n_l) * CF + c0 + c_g;
    ((uint4*)dst)[0] = ((const uint4*)tmp)[0];
    ((uint4*)dst)[1] = ((const uint4*)tmp)[1];
}

// ---------------- MFMA GEMM: K = exp((f1 f2^T - 1)/eps) ----------------
// Writes fp32 K (scattered, into d_out T region) for the accurate final pass,
// plus (H path) a coalesced fp16 shadow Kh via half-tile LDS transpose (Ct is
// 64 rows -> 34.4 KB total LDS -> 4 blocks/CU), plus per-block column-sum
// partials (= N * (K^T a0)) into ktapG[b][blockIdx.x][...].
template<bool H>
__global__ __launch_bounds__(256) void gemm_k(const f16* __restrict__ fnT,
                                              const float* __restrict__ e_in,
                                              float* __restrict__ Kf,
                                              f16* __restrict__ Kh,
                                              float* __restrict__ ktap) {
    int b  = blockIdx.z;
    int m0 = blockIdx.y * 128;
    int n0 = blockIdx.x * 128;
    const f16* A = fnT + (size_t)b       * N * CF;   // rows n
    const f16* B = fnT + (size_t)(b + 4) * N * CF;   // rows m

    __shared__ f16 As[128 * 32];
    __shared__ f16 Bs[128 * 32];
    __shared__ float cs[2][128];
    __shared__ f16 Ct[H ? 64 * 136 : 1];   // half tile; stride 136: 16B-aligned rows

    int tid = threadIdx.x;
    int w = tid >> 6;        // wave 0..3
    int l = tid & 63;        // lane
    int wr = w >> 1, wc = w & 1;

    f32x4 acc[4][4];
    #pragma unroll
    for (int i = 0; i < 4; ++i)
        #pragma unroll
        for (int j = 0; j < 4; ++j)
            acc[i][j] = (f32x4){0.f, 0.f, 0.f, 0.f};

    int srow = l >> 2;       // 0..15 within chunk
    int scp  = l & 3;        // stored chunk index c'

    for (int c0 = 0; c0 < CF; c0 += 32) {
        #pragma unroll
        for (int q = 0; q < 2; ++q) {
            int ch = w * 2 + q;          // 0..7
            int row = ch * 16 + srow;    // 0..127
            int cc = scp ^ ((row >> 1) & 3);
            async_copy16(&As[ch * 512], A + (size_t)(n0 + row) * CF + c0 + cc * 8);
            async_copy16(&Bs[ch * 512], B + (size_t)(m0 + row) * CF + c0 + cc * 8);
        }
        __syncthreads();

        f16x8 af[4], bfr[4];
        int g = l >> 4, low = l & 15;
        #pragma unroll
        for (int t = 0; t < 4; ++t) {
            int rowA = wr * 64 + t * 16 + low;
            af[t] = *(const f16x8*)(As + rowA * 32 + (g ^ ((rowA >> 1) & 3)) * 8);
            int rowB = wc * 64 + t * 16 + low;
            bfr[t] = *(const f16x8*)(Bs + rowB * 32 + (g ^ ((rowB >> 1) & 3)) * 8);
        }
        #pragma unroll
        for (int i = 0; i < 4; ++i)
            #pragma unroll
            for (int j = 0; j < 4; ++j)
                acc[i][j] = __builtin_amdgcn_mfma_f32_16x16x32_f16(af[i], bfr[j], acc[i][j], 0, 0, 0);
        __syncthreads();
    }

    float eps = expf(e_in[0]) + 0.03f;
    float inv_eps = 1.0f / eps;
    int g4 = l >> 4, low = l & 15;
    float colp[4] = {0.f, 0.f, 0.f, 0.f};
    float* out = Kf + (size_t)b * N * N;

    // fp32 K stores; keep exp'd value in acc for the fp16 staging passes
    #pragma unroll
    for (int i = 0; i < 4; ++i) {
        int rl = wr * 64 + i * 16 + g4 * 4;
        #pragma unroll
        for (int j = 0; j < 4; ++j) {
            int cl = wc * 64 + j * 16 + low;
            #pragma unroll
            for (int r = 0; r < 4; ++r) {
                float v = expf((acc[i][j][r] - 1.0f) * inv_eps);
                out[(size_t)(n0 + rl + r) * N + m0 + cl] = v;
                acc[i][j][r] = v;
                colp[j] += v;
            }
        }
    }

    // reduce column partials across g (lanes l, l+16, l+32, l+48 share a column)
    #pragma unroll
    for (int j = 0; j < 4; ++j) {
        float c = colp[j];
        c += __shfl_down(c, 32);
        c += __shfl_down(c, 16);
        if (l < 16) cs[wr][wc * 64 + j * 16 + l] = c;
    }
    __syncthreads();
    if (tid < 128)
        ktap[((size_t)b * 64 + blockIdx.x) * N + m0 + tid] =
            (cs[0][tid] + cs[1][tid]) * (1.0f / N);

    if constexpr (H) {
        f16* oh = Kh + (size_t)b * N * N;
        int row0 = tid >> 4, c8v = (tid & 15) * 8;
        #pragma unroll
        for (int half = 0; half < 2; ++half) {
            __syncthreads();
            if (wr == half) {
                #pragma unroll
                for (int i = 0; i < 4; ++i) {
                    int rl = i * 16 + g4 * 4;          // 0..63 within half
                    #pragma unroll
                    for (int j = 0; j < 4; ++j) {
                        int cl = wc * 64 + j * 16 + low;
                        #pragma unroll
                        for (int r = 0; r < 4; ++r)
                            Ct[(rl + r) * 136 + cl] = (f16)acc[i][j][r];
                    }
                }
            }
            __syncthreads();
            #pragma unroll
            for (int rr = 0; rr < 4; ++rr) {
                int row = rr * 16 + row0;
                f16x8 v = *(const f16x8*)(Ct + row * 136 + c8v);
                *(f16x8*)(oh + (size_t)(n0 + half * 64 + row) * N + m0 + c8v) = v;
            }
        }
    }
}

// ---------------- b[m] = (prob2/(KTa[m]+1e-8))^power ----------------
// KTa summed from npart slot-major partials; block = 64 cols x 4 partial-groups.
__global__ __launch_bounds__(256) void bvec_kernel(const float* __restrict__ ktap,
                                                   int npart, int slotstride,
                                                   const float* __restrict__ g_in,
                                                   const float* __restrict__ e_in,
                                                   float* __restrict__ bvec) {
    int cl = threadIdx.x & 63;
    int pg = threadIdx.x >> 6;             // 0..3
    int i = blockIdx.x * 64 + cl;          // 0..NB*N-1
    int b = i >> 12, m = i & (N - 1);
    const float* p = ktap + (size_t)b * slotstride * N + m;
    int per = npart >> 2;
    float s = 0.f;
    #pragma unroll 8
    for (int k = pg * per; k < (pg + 1) * per; ++k) s += p[(size_t)k * N];
    __shared__ float sh[4][64];
    sh[pg][cl] = s; __syncthreads();
    if (threadIdx.x < 64) {
        float tot = sh[0][cl] + sh[1][cl] + sh[2][cl] + sh[3][cl];
        float eps = expf(e_in[0]) + 0.03f;
        float gam = expf(g_in[0]);
        float power = gam / (gam + eps);
        bvec[i] = powf((1.0f / N) / (tot + 1e-8f), power);
    }
}

// ---------------- fused Sinkhorn iter, SINGLE PASS over K ----------------
// Slab = 16 rows, processed as 4 groups of 4 rows held in registers:
//   dot(K[r,:], b) -> block reduce -> a_r -> accumulate cacc += K[r,:]*a_r
// from the SAME registers. One global read per element per iteration.
// Grid (256, NB) = 1024 blocks; ~85 VGPR -> 4 blocks/CU.
template<bool H>
__global__ __launch_bounds__(256) void fused_iter(const void* __restrict__ Kp,
                                                  const float* __restrict__ bv_in,
                                                  const float* __restrict__ g_in,
                                                  const float* __restrict__ e_in,
                                                  float* __restrict__ ktap) {
    int b = blockIdx.y, slab = blockIdx.x;      // slab 0..255
    int n0s = slab * 16;
    int t = threadIdx.x;
    int w = t >> 6, l = t & 63;
    __shared__ float wred[4][4];                // [wave][row-in-group]
    float eps = expf(e_in[0]) + 0.03f;
    float gam = expf(g_in[0]);
    float power = gam / (gam + eps);
    const float* bv = bv_in + b * N;

    if constexpr (H) {
        // thread owns cols { q*2048 + t*8 + j : q=0..1, j=0..7 }
        float bl[16];
        #pragma unroll
        for (int q = 0; q < 2; ++q) {
            *(float4*)&bl[q * 8]     = *(const float4*)(bv + q * 2048 + t * 8);
            *(float4*)&bl[q * 8 + 4] = *(const float4*)(bv + q * 2048 + t * 8 + 4);
        }
        float cacc[16];
        #pragma unroll
        for (int q = 0; q < 16; ++q) cacc[q] = 0.f;
        const f16* Kb = (const f16*)Kp + ((size_t)b * N + n0s) * N;

        for (int g4 = 0; g4 < 4; ++g4) {        // 4 groups of 4 rows
            f16x8 kr[4][2];
            #pragma unroll
            for (int r = 0; r < 4; ++r)
                #pragma unroll
                for (int q = 0; q < 2; ++q)
                    kr[r][q] = *(const f16x8*)(Kb + (size_t)(g4 * 4 + r) * N + q * 2048 + t * 8);
            #pragma unroll
            for (int r = 0; r < 4; ++r) {
                float s = 0.f;
                #pragma unroll
                for (int q = 0; q < 2; ++q)
                    #pragma unroll
                    for (int j = 0; j < 8; ++j)
                        s = fmaf((float)kr[r][q][j], bl[q * 8 + j], s);
                s = wave_sum(s);
                if (l == 0) wred[w][r] = s;
            }
            __syncthreads();
            float av[4];
            #pragma unroll
            for (int r = 0; r < 4; ++r) {
                float s = wred[0][r] + wred[1][r] + wred[2][r] + wred[3][r];
                av[r] = powf((1.0f / N) / (s + 1e-8f), power);
            }
            __syncthreads();                    // wred reused next group
            #pragma unroll
            for (int r = 0; r < 4; ++r)
                #pragma unroll
                for (int q = 0; q < 2; ++q)
                    #pragma unroll
                    for (int j = 0; j < 8; ++j)
                        cacc[q * 8 + j] = fmaf((float)kr[r][q][j], av[r], cacc[q * 8 + j]);
        }
        float* o = ktap + ((size_t)b * 256 + slab) * N;
        #pragma unroll
        for (int q = 0; q < 2; ++q) {
            *(float4*)(o + q * 2048 + t * 8)     = make_float4(cacc[q*8+0], cacc[q*8+1], cacc[q*8+2], cacc[q*8+3]);
            *(float4*)(o + q * 2048 + t * 8 + 4) = make_float4(cacc[q*8+4], cacc[q*8+5], cacc[q*8+6], cacc[q*8+7]);
        }
    } else {
        // fp32 fallback: thread owns cols { q*1024 + t*4 + j : q=0..3, j=0..3 }
        int t4 = t * 4;
        float bl[16];
        #pragma unroll
        for (int q = 0; q < 4; ++q)
            *(float4*)&bl[q * 4] = *(const float4*)(bv + q * 1024 + t4);
        float cacc[16];
        #pragma unroll
        for (int q = 0; q < 16; ++q) cacc[q] = 0.f;
        const float* Kb = (const float*)Kp + ((size_t)b * N + n0s) * N;

        for (int g4 = 0; g4 < 4; ++g4) {
            float kr[4][16];
            #pragma unroll
            for (int r = 0; r < 4; ++r)
                #pragma unroll
                for (int q = 0; q < 4; ++q)
                    *(float4*)&kr[r][q * 4] = *(const float4*)(Kb + (size_t)(g4 * 4 + r) * N + q * 1024 + t4);
            #pragma unroll
            for (int r = 0; r < 4; ++r) {
                float s = 0.f;
                #pragma unroll
                for (int q = 0; q < 16; ++q) s = fmaf(kr[r][q], bl[q], s);
                s = wave_sum(s);
                if (l == 0) wred[w][r] = s;
            }
            __syncthreads();
            float av[4];
            #pragma unroll
            for (int r = 0; r < 4; ++r) {
                float s = wred[0][r] + wred[1][r] + wred[2][r] + wred[3][r];
                av[r] = powf((1.0f / N) / (s + 1e-8f), power);
            }
            __syncthreads();
            #pragma unroll
            for (int r = 0; r < 4; ++r)
                #pragma unroll
                for (int q = 0; q < 16; ++q)
                    cacc[q] = fmaf(kr[r][q], av[r], cacc[q]);
        }
        float* o = ktap + ((size_t)b * 256 + slab) * N;
        #pragma unroll
        for (int q = 0; q < 4; ++q)
            *(float4*)(o + q * 1024 + t4) =
                make_float4(cacc[q * 4], cacc[q * 4 + 1], cacc[q * 4 + 2], cacc[q * 4 + 3]);
    }
}

// ---------------- final: 4 rows/block. a5 = g(K b5) from fp32 K; T in place ----
__global__ __launch_bounds__(256) void final_k(float* __restrict__ Tout,
                                               const float* __restrict__ bv_in,
                                               const float* __restrict__ g_in,
                                               const float* __restrict__ e_in,
                                               const float* __restrict__ pc,
                                               float* __restrict__ rowsum,
                                               float* __restrict__ matches) {
    int b = blockIdx.y, n0r = blockIdx.x * 4;
    int t = threadIdx.x, w = t >> 6, l = t & 63;
    int t4 = t * 4;
    const float* bv = bv_in + b * N;
    float eps = expf(e_in[0]) + 0.03f;
    float gam = expf(g_in[0]);
    float power = gam / (gam + eps);

    float bl[16];
    #pragma unroll
    for (int q = 0; q < 4; ++q)
        *(float4*)&bl[q * 4] = *(const float4*)(bv + q * 1024 + t4);

    float* Trow0 = Tout + ((size_t)b * N + n0r) * N;
    float kv[4][16];
    #pragma unroll
    for (int r = 0; r < 4; ++r)
        #pragma unroll
        for (int q = 0; q < 4; ++q)
            *(float4*)&kv[r][q * 4] = *(const float4*)(Trow0 + (size_t)r * N + q * 1024 + t4);

    __shared__ float wred[4][4];
    #pragma unroll
    for (int r = 0; r < 4; ++r) {
        float s = 0.f;
        #pragma unroll
        for (int q = 0; q < 16; ++q) s = fmaf(kv[r][q], bl[q], s);
        s = wave_sum(s);
        if (l == 0) wred[w][r] = s;
    }
    __syncthreads();
    float av[4];
    #pragma unroll
    for (int r = 0; r < 4; ++r) {
        float s = wred[0][r] + wred[1][r] + wred[2][r] + wred[3][r];
        av[r] = powf((1.0f / N) / (s + 1e-8f), power);
    }

    const float4* c2 = (const float4*)pc + (size_t)(4 + b) * N;
    float rsv[4], s0v[4], s1v[4], s2v[4];
    #pragma unroll
    for (int r = 0; r < 4; ++r) {
        float rs = 0.f, s0 = 0.f, s1 = 0.f, s2 = 0.f;
        float an = av[r];
        #pragma unroll
        for (int q = 0; q < 4; ++q) {
            int idx = q * 1024 + t4;
            float tv0 = an * kv[r][q * 4 + 0] * bl[q * 4 + 0];
            float tv1 = an * kv[r][q * 4 + 1] * bl[q * 4 + 1];
            float tv2 = an * kv[r][q * 4 + 2] * bl[q * 4 + 2];
            float tv3 = an * kv[r][q * 4 + 3] * bl[q * 4 + 3];
            *(float4*)(Trow0 + (size_t)r * N + idx) = make_float4(tv0, tv1, tv2, tv3);
            rs += tv0 + tv1 + tv2 + tv3;
            float4 c0 = c2[idx], c1 = c2[idx + 1], cc = c2[idx + 2], c3 = c2[idx + 3];
            s0 = fmaf(tv0, c0.y, s0); s1 = fmaf(tv0, c0.z, s1); s2 = fmaf(tv0, c0.w, s2);
            s0 = fmaf(tv1, c1.y, s0); s1 = fmaf(tv1, c1.z, s1); s2 = fmaf(tv1, c1.w, s2);
            s0 = fmaf(tv2, cc.y, s0); s1 = fmaf(tv2, cc.z, s1); s2 = fmaf(tv2, cc.w, s2);
            s0 = fmaf(tv3, c3.y, s0); s1 = fmaf(tv3, c3.z, s1); s2 = fmaf(tv3, c3.w, s2);
        }
        rsv[r] = rs; s0v[r] = s0; s1v[r] = s1; s2v[r] = s2;
    }

    __shared__ float4 wred4[4][4];
    #pragma unroll
    for (int r = 0; r < 4; ++r) {
        float rs = wave_sum(rsv[r]);
        float s0 = wave_sum(s0v[r]);
        float s1 = wave_sum(s1v[r]);
        float s2 = wave_sum(s2v[r]);
        if (l == 0) wred4[w][r] = make_float4(rs, s0, s1, s2);
    }
    __syncthreads();
    if (t < 4) {
        float4 a0 = wred4[0][t], a1 = wred4[1][t], a2 = wred4[2][t], a3 = wred4[3][t];
        float4 tot = make_float4(a0.x + a1.x + a2.x + a3.x,
                                 a0.y + a1.y + a2.y + a3.y,
                                 a0.z + a1.z + a2.z + a3.z,
                                 a0.w + a1.w + a2.w + a3.w);
        rowsum[b * N + n0r + t] = tot.x;
        float inv = 1.0f / (tot.x + 1e-8f);
        float* mo = matches + ((size_t)b * N + n0r + t) * 3;
        mo[0] = tot.y * inv; mo[1] = tot.z * inv; mo[2] = tot.w * inv;
    }
}

// ---------------- weighted Kabsch with 3x3 SVD (fp64) ----------------
__global__ __launch_bounds__(256) void transform_kernel(const float* __restrict__ rowsum,
                                                        const float* __restrict__ matches,
                                                        const float* __restrict__ pc,
                                                        float* __restrict__ out) {
    int b = blockIdx.x;
    int t = threadIdx.x, w = t >> 6, l = t & 63;
    float vals[16];
    #pragma unroll
    for (int q = 0; q < 16; ++q) vals[q] = 0.f;
    for (int n = t; n < N; n += 256) {
        float wgt = rowsum[b * N + n];
        float4 c1 = ((const float4*)pc)[(size_t)b * N + n];
        float ax = c1.y, ay = c1.z, az = c1.w;
        const float* mm = matches + ((size_t)b * N + n) * 3;
        float bx = mm[0], by = mm[1], bz = mm[2];
        vals[0] += wgt;
        vals[1] = fmaf(wgt, ax, vals[1]); vals[2] = fmaf(wgt, ay, vals[2]); vals[3] = fmaf(wgt, az, vals[3]);
        vals[4] = fmaf(wgt, bx, vals[4]); vals[5] = fmaf(wgt, by, vals[5]); vals[6] = fmaf(wgt, bz, vals[6]);
        vals[7]  = fmaf(wgt * ax, bx, vals[7]);  vals[8]  = fmaf(wgt * ax, by, vals[8]);  vals[9]  = fmaf(wgt * ax, bz, vals[9]);
        vals[10] = fmaf(wgt * ay, bx, vals[10]); vals[11] = fmaf(wgt * ay, by, vals[11]); vals[12] = fmaf(wgt * ay, bz, vals[12]);
        vals[13] = fmaf(wgt * az, bx, vals[13]); vals[14] = fmaf(wgt * az, by, vals[14]); vals[15] = fmaf(wgt * az, bz, vals[15]);
    }
    __shared__ float sh[4][16];
    __shared__ float tot[16];
    #pragma unroll
    for (int q = 0; q < 16; ++q) {
        float s = wave_sum(vals[q]);
        if (l == 0) sh[w][q] = s;
    }
    __syncthreads();
    if (t < 16) tot[t] = sh[0][t] + sh[1][t] + sh[2][t] + sh[3][t];
    __syncthreads();
    if (t != 0) return;

    double S = tot[0];
    double denom = S + 1e-5;
    double Ca[3], Cb[3], M[3][3], cov[3][3];
    for (int i = 0; i < 3; ++i) { Ca[i] = tot[1 + i] / denom; Cb[i] = tot[4 + i] / denom; }
    for (int i = 0; i < 3; ++i)
        for (int j = 0; j < 3; ++j)
            M[i][j] = tot[7 + i * 3 + j] / denom;
    double s0 = S / denom;
    for (int i = 0; i < 3; ++i)
        for (int j = 0; j < 3; ++j)
            cov[i][j] = M[i][j] - Ca[i] * Cb[j] * (2.0 - s0);

    double Sm[3][3], V[3][3] = {{1,0,0},{0,1,0},{0,0,1}};
    for (int i = 0; i < 3; ++i)
        for (int j = 0; j < 3; ++j) {
            double acc = 0;
            for (int k = 0; k < 3; ++k) acc += cov[k][i] * cov[k][j];
            Sm[i][j] = acc;
        }
    for (int sweep = 0; sweep < 20; ++sweep) {
        static const int pq[3][2] = {{0,1},{0,2},{1,2}};
        for (int r = 0; r < 3; ++r) {
            int p = pq[r][0], q = pq[r][1];
            double apq = Sm[p][q];
            if (fabs(apq) < 1e-30) continue;
            double tau = (Sm[q][q] - Sm[p][p]) / (2.0 * apq);
            double t2 = (tau >= 0) ? 1.0 / (tau + sqrt(1.0 + tau * tau))
                                   : 1.0 / (tau - sqrt(1.0 + tau * tau));
            double c = 1.0 / sqrt(1.0 + t2 * t2), s = t2 * c;
            for (int i = 0; i < 3; ++i) {
                double sip = Sm[i][p], siq = Sm[i][q];
                Sm[i][p] = c * sip - s * siq; Sm[i][q] = s * sip + c * siq;
            }
            for (int j = 0; j < 3; ++j) {
                double spj = Sm[p][j], sqj = Sm[q][j];
                Sm[p][j] = c * spj - s * sqj; Sm[q][j] = s * spj + c * sqj;
            }
            for (int i = 0; i < 3; ++i) {
                double vip = V[i][p], viq = V[i][q];
                V[i][p] = c * vip - s * viq; V[i][q] = s * vip + c * viq;
            }
        }
    }
    double lam[3] = {Sm[0][0], Sm[1][1], Sm[2][2]};
    for (int i = 0; i < 2; ++i)
        for (int j = i + 1; j < 3; ++j)
            if (lam[j] > lam[i]) {
                double tl = lam[i]; lam[i] = lam[j]; lam[j] = tl;
                for (int k = 0; k < 3; ++k) { double tv = V[k][i]; V[k][i] = V[k][j]; V[k][j] = tv; }
            }
    double U[3][3];
    double sig0 = sqrt(fmax(lam[0], 0.0));
    for (int j = 0; j < 3; ++j) {
        double sig = sqrt(fmax(lam[j], 0.0));
        if (sig > 1e-12 * (sig0 + 1e-300)) {
            double nrm = 0;
            for (int i = 0; i < 3; ++i) {
                double u = cov[i][0] * V[0][j] + cov[i][1] * V[1][j] + cov[i][2] * V[2][j];
                U[i][j] = u; nrm += u * u;
            }
            nrm = 1.0 / sqrt(nrm + 1e-300);
            for (int i = 0; i < 3; ++i) U[i][j] *= nrm;
        } else {
            U[0][j] = U[1][0] * U[2][1] - U[2][0] * U[1][1];
            U[1][j] = U[2][0] * U[0][1] - U[0][0] * U[2][1];
            U[2][j] = U[0][0] * U[1][1] - U[1][0] * U[0][1];
        }
    }
    double R[3][3];
    for (int i = 0; i < 3; ++i)
        for (int j = 0; j < 3; ++j)
            R[i][j] = V[i][0] * U[j][0] + V[i][1] * U[j][1] + V[i][2] * U[j][2];
    double det = R[0][0] * (R[1][1] * R[2][2] - R[1][2] * R[2][1])
               - R[0][1] * (R[1][0] * R[2][2] - R[1][2] * R[2][0])
               + R[0][2] * (R[1][0] * R[2][1] - R[1][1] * R[2][0]);
    if (!(det > 0)) {
        for (int k = 0; k < 3; ++k) V[k][2] = -V[k][2];
        for (int i = 0; i < 3; ++i)
            for (int j = 0; j < 3; ++j)
                R[i][j] = V[i][0] * U[j][0] + V[i][1] * U[j][1] + V[i][2] * U[j][2];
    }
    double tr[3];
    for (int i = 0; i < 3; ++i)
        tr[i] = -(R[i][0] * Ca[0] + R[i][1] * Ca[1] + R[i][2] * Ca[2]) + Cb[i];
    float* o = out + b * 12;
    for (int i = 0; i < 3; ++i) {
        o[i * 4 + 0] = (float)R[i][0];
        o[i * 4 + 1] = (float)R[i][1];
        o[i * 4 + 2] = (float)R[i][2];
        o[i * 4 + 3] = (float)tr[i];
    }
}

extern "C" void kernel_launch(void* const* d_in, const int* in_sizes, int n_in,
                              void* d_out, int out_size, void* d_ws, size_t ws_size,
                              hipStream_t stream) {
    const float* pf   = (const float*)d_in[0];
    const float* pc   = (const float*)d_in[1];
    const float* g_in = (const float*)d_in[2];
    const float* e_in = (const float*)d_in[3];

    char* wsb = (char*)d_ws;
    f16*   fnT   = (f16*)(wsb + OFF_FNT);
    float* rnorm = (float*)(wsb + OFF_RNORM);
    float* bvec  = (float*)(wsb + OFF_BVEC);

    float* T_out   = (float*)d_out;
    float* matches = T_out + (size_t)NB * N * N;
    float* trans   = matches + (size_t)NB * N * 3;
    // rnorm consumed by transpose_kernel before final_k runs -> safe alias
    float* rowsum  = rnorm;

    rnorm_kernel<<<dim3(8 * N / 256), 256, 0, stream>>>(pf, rnorm);
    transpose_kernel<<<dim3(CF / 64, N / 64, 8), 256, 0, stream>>>(pf, rnorm, fnT);

    // fused_iter partials reuse the fnT region (dead after gemm_k)
    float* ktapF = (float*)(wsb + OFF_FNT);

    if (ws_size >= (size_t)REQ_H) {
        // fp32 K in d_out T region (for accurate final), fp16 shadow for Sinkhorn.
        f16*   Kh    = (f16*)(wsb + OFF_SCR);
        float* ktapG = (float*)(wsb + OFF_KTAP);
        gemm_k<true><<<dim3(N / 128, N / 128, NB), 256, 0, stream>>>(fnT, e_in, T_out, Kh, ktapG);
        bvec_kernel<<<dim3(NB * N / 64), 256, 0, stream>>>(ktapG, 32, 64, g_in, e_in, bvec);
        for (int it = 0; it < 4; ++it) {
            fused_iter<true><<<dim3(N / 16, NB), 256, 0, stream>>>(Kh, bvec, g_in, e_in, ktapF);
            bvec_kernel<<<dim3(NB * N / 64), 256, 0, stream>>>(ktapF, 256, 256, g_in, e_in, bvec);
        }
        final_k<<<dim3(N / 4, NB), 256, 0, stream>>>(T_out, bvec, g_in, e_in, pc, rowsum, matches);
    } else {
        // fallback: fp32 K everywhere (Sinkhorn reads fp32 K from T region)
        float* ktapG = (float*)(wsb + OFF_SCR);
        gemm_k<false><<<dim3(N / 128, N / 128, NB), 256, 0, stream>>>(fnT, e_in, T_out, (f16*)nullptr, ktapG);
        bvec_kernel<<<dim3(NB * N / 64), 256, 0, stream>>>(ktapG, 32, 64, g_in, e_in, bvec);
        for (int it = 0; it < 4; ++it) {
            fused_iter<false><<<dim3(N / 16, NB), 256, 0, stream>>>(T_out, bvec, g_in, e_in, ktapF);
            bvec_kernel<<<dim3(NB * N / 64), 256, 0, stream>>>(ktapF, 256, 256, g_in, e_in, bvec);
        }
        final_k<<<dim3(N / 4, NB), 256, 0, stream>>>(T_out, bvec, g_in, e_in, pc, rowsum, matches);
    }

    transform_kernel<<<dim3(NB), 256, 0, stream>>>(rowsum, matches, pc, trans);
}

// Round 9
// 837.594 us; speedup vs baseline: 1.0397x; 1.0397x over previous
//
#include <hip/hip_runtime.h>
#include <math.h>

#define NB 4        // batch pairs
#define N 4096      // points
#define CF 640      // feature dim

typedef _Float16 f16;
typedef _Float16 f16x8 __attribute__((ext_vector_type(8)));
typedef _Float16 f16x4 __attribute__((ext_vector_type(4)));
typedef float    f32x4 __attribute__((ext_vector_type(4)));
typedef unsigned int u32;

// ---------------- workspace layout (byte offsets) ----------------
// fnT  : 8*N*CF fp16 (normalized features, (b,n,c)); DEAD after gemm_k ->
//        reused as ktapF (NB*256*N f32 = 16.8MB <= 41.9MB) by fused_iter.
// rnorm: 8*N float  (aliased as rowsum later)
// bvec : NB*N float
// Kh   : NB*N*N fp16 (fp16 shadow of K for Sinkhorn)
// ktapG: NB*64*N f32 (gemm-folded first column-sum partials, 32 slots used)
// fp32 K itself lives in d_out's T region (finalized in place).
#define OFF_FNT   0ll
#define OFF_RNORM (OFF_FNT + 8ll*N*CF*2)
#define OFF_BVEC  (OFF_RNORM + 8ll*N*4)
#define OFF_SCR   (OFF_BVEC + (long long)NB*N*4)
#define OFF_KTAP  (OFF_SCR + (long long)NB*N*N*2)
#define REQ_H     (OFF_KTAP + (long long)NB*64*N*4)
#define REQ_F     (OFF_SCR + (long long)NB*64*N*4)

__device__ inline void async_copy16(void* lds, const void* g) {
    __builtin_amdgcn_global_load_lds(
        (const __attribute__((address_space(1))) u32*)g,
        (__attribute__((address_space(3))) u32*)lds,
        16, 0, 0);
}

__device__ inline float wave_sum(float s) {
    s += __shfl_down(s, 32);
    s += __shfl_down(s, 16);
    s += __shfl_down(s, 8);
    s += __shfl_down(s, 4);
    s += __shfl_down(s, 2);
    s += __shfl_down(s, 1);
    return s;
}

// butterfly: every lane ends with the full sum (no broadcast needed)
__device__ inline float wave_sum_all(float s) {
    #pragma unroll
    for (int k = 1; k < 64; k <<= 1) s += __shfl_xor(s, k);
    return s;
}

// ---------------- pass 1: per-point inverse norms ----------------
__global__ __launch_bounds__(256) void rnorm_kernel(const float* __restrict__ pf,
                                                    float* __restrict__ rnorm) {
    int idx = blockIdx.x * 256 + threadIdx.x;   // over 8*4096
    int n = idx & (N - 1);
    int b = idx >> 12;
    const float* src = pf + (size_t)b * CF * N + n;
    float s = 0.f;
    for (int c = 0; c < CF; ++c) { float v = src[(size_t)c * N]; s = fmaf(v, v, s); }
    rnorm[idx] = 1.0f / sqrtf(s + 1e-8f);
}

// ---------------- pass 2: transpose (c,n)->(n,c), scale, fp16 ----------------
__global__ __launch_bounds__(256) void transpose_kernel(const float* __restrict__ pf,
                                                        const float* __restrict__ rnorm,
                                                        f16* __restrict__ fnT) {
    __shared__ float tile[64][65];
    int b  = blockIdx.z;
    int c0 = blockIdx.x * 64;
    int n1 = blockIdx.y * 64;
    int t  = threadIdx.x;

    int c_l = t >> 4;               // 0..15
    int n_l4 = (t & 15) * 4;        // 0..60
    #pragma unroll
    for (int i = 0; i < 4; ++i) {
        int c = c_l + i * 16;
        float4 v = *(const float4*)(pf + (size_t)(b * CF + c0 + c) * N + n1 + n_l4);
        tile[c][n_l4 + 0] = v.x; tile[c][n_l4 + 1] = v.y;
        tile[c][n_l4 + 2] = v.z; tile[c][n_l4 + 3] = v.w;
    }
    __syncthreads();

    int n_l = t >> 2;               // 0..63
    int c_g = (t & 3) * 16;         // 0,16,32,48
    float rn = rnorm[b * N + n1 + n_l];
    f16 tmp[16] __attribute__((aligned(16)));
    #pragma unroll
    for (int i = 0; i < 16; ++i)
        tmp[i] = (f16)(tile[c_g + i][n_l] * rn);
    f16* dst = fnT + (size_t)(b * N + n1 + n_l) * CF + c0 + c_g;
    ((uint4*)dst)[0] = ((const uint4*)tmp)[0];
    ((uint4*)dst)[1] = ((const uint4*)tmp)[1];
}

// ---------------- MFMA GEMM: K = exp((f1 f2^T - 1)/eps) ----------------
// Writes fp32 K (scattered, into d_out T region) for the accurate final pass,
// plus (H path) a coalesced fp16 shadow Kh via half-tile LDS transpose (Ct is
// 64 rows -> 34.4 KB total LDS -> 4 blocks/CU), plus per-block column-sum
// partials (= N * (K^T a0)) into ktapG[b][blockIdx.x][...].
template<bool H>
__global__ __launch_bounds__(256) void gemm_k(const f16* __restrict__ fnT,
                                              const float* __restrict__ e_in,
                                              float* __restrict__ Kf,
                                              f16* __restrict__ Kh,
                                              float* __restrict__ ktap) {
    int b  = blockIdx.z;
    int m0 = blockIdx.y * 128;
    int n0 = blockIdx.x * 128;
    const f16* A = fnT + (size_t)b       * N * CF;   // rows n
    const f16* B = fnT + (size_t)(b + 4) * N * CF;   // rows m

    __shared__ f16 As[128 * 32];
    __shared__ f16 Bs[128 * 32];
    __shared__ float cs[2][128];
    __shared__ f16 Ct[H ? 64 * 136 : 1];   // half tile; stride 136: 16B-aligned rows

    int tid = threadIdx.x;
    int w = tid >> 6;        // wave 0..3
    int l = tid & 63;        // lane
    int wr = w >> 1, wc = w & 1;

    f32x4 acc[4][4];
    #pragma unroll
    for (int i = 0; i < 4; ++i)
        #pragma unroll
        for (int j = 0; j < 4; ++j)
            acc[i][j] = (f32x4){0.f, 0.f, 0.f, 0.f};

    int srow = l >> 2;       // 0..15 within chunk
    int scp  = l & 3;        // stored chunk index c'

    for (int c0 = 0; c0 < CF; c0 += 32) {
        #pragma unroll
        for (int q = 0; q < 2; ++q) {
            int ch = w * 2 + q;          // 0..7
            int row = ch * 16 + srow;    // 0..127
            int cc = scp ^ ((row >> 1) & 3);
            async_copy16(&As[ch * 512], A + (size_t)(n0 + row) * CF + c0 + cc * 8);
            async_copy16(&Bs[ch * 512], B + (size_t)(m0 + row) * CF + c0 + cc * 8);
        }
        __syncthreads();

        f16x8 af[4], bfr[4];
        int g = l >> 4, low = l & 15;
        #pragma unroll
        for (int t = 0; t < 4; ++t) {
            int rowA = wr * 64 + t * 16 + low;
            af[t] = *(const f16x8*)(As + rowA * 32 + (g ^ ((rowA >> 1) & 3)) * 8);
            int rowB = wc * 64 + t * 16 + low;
            bfr[t] = *(const f16x8*)(Bs + rowB * 32 + (g ^ ((rowB >> 1) & 3)) * 8);
        }
        #pragma unroll
        for (int i = 0; i < 4; ++i)
            #pragma unroll
            for (int j = 0; j < 4; ++j)
                acc[i][j] = __builtin_amdgcn_mfma_f32_16x16x32_f16(af[i], bfr[j], acc[i][j], 0, 0, 0);
        __syncthreads();
    }

    float eps = expf(e_in[0]) + 0.03f;
    float inv_eps = 1.0f / eps;
    int g4 = l >> 4, low = l & 15;
    float colp[4] = {0.f, 0.f, 0.f, 0.f};
    float* out = Kf + (size_t)b * N * N;

    // fp32 K stores; keep exp'd value in acc for the fp16 staging passes
    #pragma unroll
    for (int i = 0; i < 4; ++i) {
        int rl = wr * 64 + i * 16 + g4 * 4;
        #pragma unroll
        for (int j = 0; j < 4; ++j) {
            int cl = wc * 64 + j * 16 + low;
            #pragma unroll
            for (int r = 0; r < 4; ++r) {
                float v = expf((acc[i][j][r] - 1.0f) * inv_eps);
                out[(size_t)(n0 + rl + r) * N + m0 + cl] = v;
                acc[i][j][r] = v;
                colp[j] += v;
            }
        }
    }

    // reduce column partials across g (lanes l, l+16, l+32, l+48 share a column)
    #pragma unroll
    for (int j = 0; j < 4; ++j) {
        float c = colp[j];
        c += __shfl_down(c, 32);
        c += __shfl_down(c, 16);
        if (l < 16) cs[wr][wc * 64 + j * 16 + l] = c;
    }
    __syncthreads();
    if (tid < 128)
        ktap[((size_t)b * 64 + blockIdx.x) * N + m0 + tid] =
            (cs[0][tid] + cs[1][tid]) * (1.0f / N);

    if constexpr (H) {
        f16* oh = Kh + (size_t)b * N * N;
        int row0 = tid >> 4, c8v = (tid & 15) * 8;
        #pragma unroll
        for (int half = 0; half < 2; ++half) {
            __syncthreads();
            if (wr == half) {
                #pragma unroll
                for (int i = 0; i < 4; ++i) {
                    int rl = i * 16 + g4 * 4;          // 0..63 within half
                    #pragma unroll
                    for (int j = 0; j < 4; ++j) {
                        int cl = wc * 64 + j * 16 + low;
                        #pragma unroll
                        for (int r = 0; r < 4; ++r)
                            Ct[(rl + r) * 136 + cl] = (f16)acc[i][j][r];
                    }
                }
            }
            __syncthreads();
            #pragma unroll
            for (int rr = 0; rr < 4; ++rr) {
                int row = rr * 16 + row0;
                f16x8 v = *(const f16x8*)(Ct + row * 136 + c8v);
                *(f16x8*)(oh + (size_t)(n0 + half * 64 + row) * N + m0 + c8v) = v;
            }
        }
    }
}

// ---------------- b[m] = (prob2/(KTa[m]+1e-8))^power ----------------
// KTa summed from npart slot-major partials; block = 64 cols x 4 partial-groups.
__global__ __launch_bounds__(256) void bvec_kernel(const float* __restrict__ ktap,
                                                   int npart, int slotstride,
                                                   const float* __restrict__ g_in,
                                                   const float* __restrict__ e_in,
                                                   float* __restrict__ bvec) {
    int cl = threadIdx.x & 63;
    int pg = threadIdx.x >> 6;             // 0..3
    int i = blockIdx.x * 64 + cl;          // 0..NB*N-1
    int b = i >> 12, m = i & (N - 1);
    const float* p = ktap + (size_t)b * slotstride * N + m;
    int per = npart >> 2;
    float s = 0.f;
    #pragma unroll 8
    for (int k = pg * per; k < (pg + 1) * per; ++k) s += p[(size_t)k * N];
    __shared__ float sh[4][64];
    sh[pg][cl] = s; __syncthreads();
    if (threadIdx.x < 64) {
        float tot = sh[0][cl] + sh[1][cl] + sh[2][cl] + sh[3][cl];
        float eps = expf(e_in[0]) + 0.03f;
        float gam = expf(g_in[0]);
        float power = gam / (gam + eps);
        bvec[i] = powf((1.0f / N) / (tot + 1e-8f), power);
    }
}

// ---------------- fused Sinkhorn iter, SINGLE PASS over K ----------------
// Round-5 measured-safe structure (16-row slab, thread owns 16 cols, LDS wred),
// but row-groups of 8 instead of 4: barrier pairs per slab drop 4 -> 2.
// kr[8][2] f16x8 = 64 VGPR held per group; ~120 VGPR total, no spill.
template<bool H>
__global__ __launch_bounds__(256) void fused_iter(const void* __restrict__ Kp,
                                                  const float* __restrict__ bv_in,
                                                  const float* __restrict__ g_in,
                                                  const float* __restrict__ e_in,
                                                  float* __restrict__ ktap) {
    int b = blockIdx.y, slab = blockIdx.x;      // slab 0..255
    int n0s = slab * 16;
    int t = threadIdx.x;
    int w = t >> 6, l = t & 63;
    __shared__ float wred[4][8];                // [wave][row-in-group]
    float eps = expf(e_in[0]) + 0.03f;
    float gam = expf(g_in[0]);
    float power = gam / (gam + eps);
    const float* bv = bv_in + b * N;

    if constexpr (H) {
        // thread owns cols { q*2048 + t*8 + j : q=0..1, j=0..7 }
        float bl[16];
        #pragma unroll
        for (int q = 0; q < 2; ++q) {
            *(float4*)&bl[q * 8]     = *(const float4*)(bv + q * 2048 + t * 8);
            *(float4*)&bl[q * 8 + 4] = *(const float4*)(bv + q * 2048 + t * 8 + 4);
        }
        float cacc[16];
        #pragma unroll
        for (int q = 0; q < 16; ++q) cacc[q] = 0.f;
        const f16* Kb = (const f16*)Kp + ((size_t)b * N + n0s) * N;

        for (int g8 = 0; g8 < 2; ++g8) {        // 2 groups of 8 rows
            f16x8 kr[8][2];
            #pragma unroll
            for (int r = 0; r < 8; ++r)
                #pragma unroll
                for (int q = 0; q < 2; ++q)
                    kr[r][q] = *(const f16x8*)(Kb + (size_t)(g8 * 8 + r) * N + q * 2048 + t * 8);
            #pragma unroll
            for (int r = 0; r < 8; ++r) {
                float s = 0.f;
                #pragma unroll
                for (int q = 0; q < 2; ++q)
                    #pragma unroll
                    for (int j = 0; j < 8; ++j)
                        s = fmaf((float)kr[r][q][j], bl[q * 8 + j], s);
                s = wave_sum(s);
                if (l == 0) wred[w][r] = s;
            }
            __syncthreads();
            float av[8];
            #pragma unroll
            for (int r = 0; r < 8; ++r) {
                float s = wred[0][r] + wred[1][r] + wred[2][r] + wred[3][r];
                av[r] = powf((1.0f / N) / (s + 1e-8f), power);
            }
            __syncthreads();                    // wred reused next group
            #pragma unroll
            for (int r = 0; r < 8; ++r)
                #pragma unroll
                for (int q = 0; q < 2; ++q)
                    #pragma unroll
                    for (int j = 0; j < 8; ++j)
                        cacc[q * 8 + j] = fmaf((float)kr[r][q][j], av[r], cacc[q * 8 + j]);
        }
        float* o = ktap + ((size_t)b * 256 + slab) * N;
        #pragma unroll
        for (int q = 0; q < 2; ++q) {
            *(float4*)(o + q * 2048 + t * 8)     = make_float4(cacc[q*8+0], cacc[q*8+1], cacc[q*8+2], cacc[q*8+3]);
            *(float4*)(o + q * 2048 + t * 8 + 4) = make_float4(cacc[q*8+4], cacc[q*8+5], cacc[q*8+6], cacc[q*8+7]);
        }
    } else {
        // fp32 fallback: thread owns cols { q*1024 + t*4 + j : q=0..3, j=0..3 }
        int t4 = t * 4;
        float bl[16];
        #pragma unroll
        for (int q = 0; q < 4; ++q)
            *(float4*)&bl[q * 4] = *(const float4*)(bv + q * 1024 + t4);
        float cacc[16];
        #pragma unroll
        for (int q = 0; q < 16; ++q) cacc[q] = 0.f;
        const float* Kb = (const float*)Kp + ((size_t)b * N + n0s) * N;

        for (int g4 = 0; g4 < 4; ++g4) {
            float kr[4][16];
            #pragma unroll
            for (int r = 0; r < 4; ++r)
                #pragma unroll
                for (int q = 0; q < 4; ++q)
                    *(float4*)&kr[r][q * 4] = *(const float4*)(Kb + (size_t)(g4 * 4 + r) * N + q * 1024 + t4);
            #pragma unroll
            for (int r = 0; r < 4; ++r) {
                float s = 0.f;
                #pragma unroll
                for (int q = 0; q < 16; ++q) s = fmaf(kr[r][q], bl[q], s);
                s = wave_sum(s);
                if (l == 0) wred[w][r] = s;
            }
            __syncthreads();
            float av[4];
            #pragma unroll
            for (int r = 0; r < 4; ++r) {
                float s = wred[0][r] + wred[1][r] + wred[2][r] + wred[3][r];
                av[r] = powf((1.0f / N) / (s + 1e-8f), power);
            }
            __syncthreads();
            #pragma unroll
            for (int r = 0; r < 4; ++r)
                #pragma unroll
                for (int q = 0; q < 16; ++q)
                    cacc[q] = fmaf(kr[r][q], av[r], cacc[q]);
        }
        float* o = ktap + ((size_t)b * 256 + slab) * N;
        #pragma unroll
        for (int q = 0; q < 4; ++q)
            *(float4*)(o + q * 1024 + t4) =
                make_float4(cacc[q * 4], cacc[q * 4 + 1], cacc[q * 4 + 2], cacc[q * 4 + 3]);
    }
}

// ---------------- final: barrier-free, 1 row per WAVE ----------------
// a5 = g(K b5) from fp32 K (in T region); T = a K b^T in place; rowsum/matches.
// No LDS, no __syncthreads: shfl_xor reductions only -> loads stay in flight.
__global__ __launch_bounds__(256) void final_k(float* __restrict__ Tout,
                                               const float* __restrict__ bv_in,
                                               const float* __restrict__ g_in,
                                               const float* __restrict__ e_in,
                                               const float* __restrict__ pc,
                                               float* __restrict__ rowsum,
                                               float* __restrict__ matches) {
    int b = blockIdx.y;
    int t = threadIdx.x, w = t >> 6, l = t & 63;
    int n = blockIdx.x * 4 + w;                 // wave owns one row
    float eps = expf(e_in[0]) + 0.03f;
    float gam = expf(g_in[0]);
    float power = gam / (gam + eps);
    const float* bv = bv_in + b * N;
    float* Trow = Tout + ((size_t)b * N + n) * N;

    // lane owns cols { q*256 + l*4 : q=0..15 }
    float bl[64], kv[64];
    #pragma unroll
    for (int q = 0; q < 16; ++q) {
        int col = q * 256 + l * 4;
        *(float4*)&bl[q * 4] = *(const float4*)(bv + col);
        *(float4*)&kv[q * 4] = *(const float4*)(Trow + col);
    }
    float s = 0.f;
    #pragma unroll
    for (int q = 0; q < 64; ++q) s = fmaf(kv[q], bl[q], s);
    s = wave_sum_all(s);
    float an = powf((1.0f / N) / (s + 1e-8f), power);

    const float4* c2 = (const float4*)pc + (size_t)(4 + b) * N;
    float rs = 0.f, s0 = 0.f, s1 = 0.f, s2 = 0.f;
    #pragma unroll
    for (int q = 0; q < 16; ++q) {
        int col = q * 256 + l * 4;
        float tv0 = an * kv[q * 4 + 0] * bl[q * 4 + 0];
        float tv1 = an * kv[q * 4 + 1] * bl[q * 4 + 1];
        float tv2 = an * kv[q * 4 + 2] * bl[q * 4 + 2];
        float tv3 = an * kv[q * 4 + 3] * bl[q * 4 + 3];
        *(float4*)(Trow + col) = make_float4(tv0, tv1, tv2, tv3);
        rs += tv0 + tv1 + tv2 + tv3;
        float4 c0 = c2[col], c1 = c2[col + 1], cc = c2[col + 2], c3 = c2[col + 3];
        s0 = fmaf(tv0, c0.y, s0); s1 = fmaf(tv0, c0.z, s1); s2 = fmaf(tv0, c0.w, s2);
        s0 = fmaf(tv1, c1.y, s0); s1 = fmaf(tv1, c1.z, s1); s2 = fmaf(tv1, c1.w, s2);
        s0 = fmaf(tv2, cc.y, s0); s1 = fmaf(tv2, cc.z, s1); s2 = fmaf(tv2, cc.w, s2);
        s0 = fmaf(tv3, c3.y, s0); s1 = fmaf(tv3, c3.z, s1); s2 = fmaf(tv3, c3.w, s2);
    }
    rs = wave_sum_all(rs);
    s0 = wave_sum_all(s0);
    s1 = wave_sum_all(s1);
    s2 = wave_sum_all(s2);
    if (l == 0) {
        rowsum[b * N + n] = rs;
        float inv = 1.0f / (rs + 1e-8f);
        float* mo = matches + ((size_t)b * N + n) * 3;
        mo[0] = s0 * inv; mo[1] = s1 * inv; mo[2] = s2 * inv;
    }
}

// ---------------- weighted Kabsch with 3x3 SVD (fp64) ----------------
__global__ __launch_bounds__(256) void transform_kernel(const float* __restrict__ rowsum,
                                                        const float* __restrict__ matches,
                                                        const float* __restrict__ pc,
                                                        float* __restrict__ out) {
    int b = blockIdx.x;
    int t = threadIdx.x, w = t >> 6, l = t & 63;
    float vals[16];
    #pragma unroll
    for (int q = 0; q < 16; ++q) vals[q] = 0.f;
    for (int n = t; n < N; n += 256) {
        float wgt = rowsum[b * N + n];
        float4 c1 = ((const float4*)pc)[(size_t)b * N + n];
        float ax = c1.y, ay = c1.z, az = c1.w;
        const float* mm = matches + ((size_t)b * N + n) * 3;
        float bx = mm[0], by = mm[1], bz = mm[2];
        vals[0] += wgt;
        vals[1] = fmaf(wgt, ax, vals[1]); vals[2] = fmaf(wgt, ay, vals[2]); vals[3] = fmaf(wgt, az, vals[3]);
        vals[4] = fmaf(wgt, bx, vals[4]); vals[5] = fmaf(wgt, by, vals[5]); vals[6] = fmaf(wgt, bz, vals[6]);
        vals[7]  = fmaf(wgt * ax, bx, vals[7]);  vals[8]  = fmaf(wgt * ax, by, vals[8]);  vals[9]  = fmaf(wgt * ax, bz, vals[9]);
        vals[10] = fmaf(wgt * ay, bx, vals[10]); vals[11] = fmaf(wgt * ay, by, vals[11]); vals[12] = fmaf(wgt * ay, bz, vals[12]);
        vals[13] = fmaf(wgt * az, bx, vals[13]); vals[14] = fmaf(wgt * az, by, vals[14]); vals[15] = fmaf(wgt * az, bz, vals[15]);
    }
    __shared__ float sh[4][16];
    __shared__ float tot[16];
    #pragma unroll
    for (int q = 0; q < 16; ++q) {
        float s = wave_sum(vals[q]);
        if (l == 0) sh[w][q] = s;
    }
    __syncthreads();
    if (t < 16) tot[t] = sh[0][t] + sh[1][t] + sh[2][t] + sh[3][t];
    __syncthreads();
    if (t != 0) return;

    double S = tot[0];
    double denom = S + 1e-5;
    double Ca[3], Cb[3], M[3][3], cov[3][3];
    for (int i = 0; i < 3; ++i) { Ca[i] = tot[1 + i] / denom; Cb[i] = tot[4 + i] / denom; }
    for (int i = 0; i < 3; ++i)
        for (int j = 0; j < 3; ++j)
            M[i][j] = tot[7 + i * 3 + j] / denom;
    double s0 = S / denom;
    for (int i = 0; i < 3; ++i)
        for (int j = 0; j < 3; ++j)
            cov[i][j] = M[i][j] - Ca[i] * Cb[j] * (2.0 - s0);

    double Sm[3][3], V[3][3] = {{1,0,0},{0,1,0},{0,0,1}};
    for (int i = 0; i < 3; ++i)
        for (int j = 0; j < 3; ++j) {
            double acc = 0;
            for (int k = 0; k < 3; ++k) acc += cov[k][i] * cov[k][j];
            Sm[i][j] = acc;
        }
    for (int sweep = 0; sweep < 20; ++sweep) {
        static const int pq[3][2] = {{0,1},{0,2},{1,2}};
        for (int r = 0; r < 3; ++r) {
            int p = pq[r][0], q = pq[r][1];
            double apq = Sm[p][q];
            if (fabs(apq) < 1e-30) continue;
            double tau = (Sm[q][q] - Sm[p][p]) / (2.0 * apq);
            double t2 = (tau >= 0) ? 1.0 / (tau + sqrt(1.0 + tau * tau))
                                   : 1.0 / (tau - sqrt(1.0 + tau * tau));
            double c = 1.0 / sqrt(1.0 + t2 * t2), s = t2 * c;
            for (int i = 0; i < 3; ++i) {
                double sip = Sm[i][p], siq = Sm[i][q];
                Sm[i][p] = c * sip - s * siq; Sm[i][q] = s * sip + c * siq;
            }
            for (int j = 0; j < 3; ++j) {
                double spj = Sm[p][j], sqj = Sm[q][j];
                Sm[p][j] = c * spj - s * sqj; Sm[q][j] = s * spj + c * sqj;
            }
            for (int i = 0; i < 3; ++i) {
                double vip = V[i][p], viq = V[i][q];
                V[i][p] = c * vip - s * viq; V[i][q] = s * vip + c * viq;
            }
        }
    }
    double lam[3] = {Sm[0][0], Sm[1][1], Sm[2][2]};
    for (int i = 0; i < 2; ++i)
        for (int j = i + 1; j < 3; ++j)
            if (lam[j] > lam[i]) {
                double tl = lam[i]; lam[i] = lam[j]; lam[j] = tl;
                for (int k = 0; k < 3; ++k) { double tv = V[k][i]; V[k][i] = V[k][j]; V[k][j] = tv; }
            }
    double U[3][3];
    double sig0 = sqrt(fmax(lam[0], 0.0));
    for (int j = 0; j < 3; ++j) {
        double sig = sqrt(fmax(lam[j], 0.0));
        if (sig > 1e-12 * (sig0 + 1e-300)) {
            double nrm = 0;
            for (int i = 0; i < 3; ++i) {
                double u = cov[i][0] * V[0][j] + cov[i][1] * V[1][j] + cov[i][2] * V[2][j];
                U[i][j] = u; nrm += u * u;
            }
            nrm = 1.0 / sqrt(nrm + 1e-300);
            for (int i = 0; i < 3; ++i) U[i][j] *= nrm;
        } else {
            U[0][j] = U[1][0] * U[2][1] - U[2][0] * U[1][1];
            U[1][j] = U[2][0] * U[0][1] - U[0][0] * U[2][1];
            U[2][j] = U[0][0] * U[1][1] - U[1][0] * U[0][1];
        }
    }
    double R[3][3];
    for (int i = 0; i < 3; ++i)
        for (int j = 0; j < 3; ++j)
            R[i][j] = V[i][0] * U[j][0] + V[i][1] * U[j][1] + V[i][2] * U[j][2];
    double det = R[0][0] * (R[1][1] * R[2][2] - R[1][2] * R[2][1])
               - R[0][1] * (R[1][0] * R[2][2] - R[1][2] * R[2][0])
               + R[0][2] * (R[1][0] * R[2][1] - R[1][1] * R[2][0]);
    if (!(det > 0)) {
        for (int k = 0; k < 3; ++k) V[k][2] = -V[k][2];
        for (int i = 0; i < 3; ++i)
            for (int j = 0; j < 3; ++j)
                R[i][j] = V[i][0] * U[j][0] + V[i][1] * U[j][1] + V[i][2] * U[j][2];
    }
    double tr[3];
    for (int i = 0; i < 3; ++i)
        tr[i] = -(R[i][0] * Ca[0] + R[i][1] * Ca[1] + R[i][2] * Ca[2]) + Cb[i];
    float* o = out + b * 12;
    for (int i = 0; i < 3; ++i) {
        o[i * 4 + 0] = (float)R[i][0];
        o[i * 4 + 1] = (float)R[i][1];
        o[i * 4 + 2] = (float)R[i][2];
        o[i * 4 + 3] = (float)tr[i];
    }
}

extern "C" void kernel_launch(void* const* d_in, const int* in_sizes, int n_in,
                              void* d_out, int out_size, void* d_ws, size_t ws_size,
                              hipStream_t stream) {
    const float* pf   = (const float*)d_in[0];
    const float* pc   = (const float*)d_in[1];
    const float* g_in = (const float*)d_in[2];
    const float* e_in = (const float*)d_in[3];

    char* wsb = (char*)d_ws;
    f16*   fnT   = (f16*)(wsb + OFF_FNT);
    float* rnorm = (float*)(wsb + OFF_RNORM);
    float* bvec  = (float*)(wsb + OFF_BVEC);

    float* T_out   = (float*)d_out;
    float* matches = T_out + (size_t)NB * N * N;
    float* trans   = matches + (size_t)NB * N * 3;
    // rnorm consumed by transpose_kernel before final_k runs -> safe alias
    float* rowsum  = rnorm;

    rnorm_kernel<<<dim3(8 * N / 256), 256, 0, stream>>>(pf, rnorm);
    transpose_kernel<<<dim3(CF / 64, N / 64, 8), 256, 0, stream>>>(pf, rnorm, fnT);

    // fused_iter partials reuse the fnT region (dead after gemm_k)
    float* ktapF = (float*)(wsb + OFF_FNT);

    if (ws_size >= (size_t)REQ_H) {
        // fp32 K in d_out T region (for accurate final), fp16 shadow for Sinkhorn.
        f16*   Kh    = (f16*)(wsb + OFF_SCR);
        float* ktapG = (float*)(wsb + OFF_KTAP);
        gemm_k<true><<<dim3(N / 128, N / 128, NB), 256, 0, stream>>>(fnT, e_in, T_out, Kh, ktapG);
        bvec_kernel<<<dim3(NB * N / 64), 256, 0, stream>>>(ktapG, 32, 64, g_in, e_in, bvec);
        for (int it = 0; it < 4; ++it) {
            fused_iter<true><<<dim3(N / 16, NB), 256, 0, stream>>>(Kh, bvec, g_in, e_in, ktapF);
            bvec_kernel<<<dim3(NB * N / 64), 256, 0, stream>>>(ktapF, 256, 256, g_in, e_in, bvec);
        }
        final_k<<<dim3(N / 4, NB), 256, 0, stream>>>(T_out, bvec, g_in, e_in, pc, rowsum, matches);
    } else {
        // fallback: fp32 K everywhere (Sinkhorn reads fp32 K from T region)
        float* ktapG = (float*)(wsb + OFF_SCR);
        gemm_k<false><<<dim3(N / 128, N / 128, NB), 256, 0, stream>>>(fnT, e_in, T_out, (f16*)nullptr, ktapG);
        bvec_kernel<<<dim3(NB * N / 64), 256, 0, stream>>>(ktapG, 32, 64, g_in, e_in, bvec);
        for (int it = 0; it < 4; ++it) {
            fused_iter<false><<<dim3(N / 16, NB), 256, 0, stream>>>(T_out, bvec, g_in, e_in, ktapF);
            bvec_kernel<<<dim3(NB * N / 64), 256, 0, stream>>>(ktapF, 256, 256, g_in, e_in, bvec);
        }
        final_k<<<dim3(N / 4, NB), 256, 0, stream>>>(T_out, bvec, g_in, e_in, pc, rowsum, matches);
    }

    transform_kernel<<<dim3(NB), 256, 0, stream>>>(rowsum, matches, pc, trans);
}